// Round 6
// baseline (148.723 us; speedup 1.0000x reference)
//
#include <hip/hip_runtime.h>

// ---------------------------------------------------------------------------
// CustomDeformableDetrMLPPredictionHead — MI355X (gfx950), round 16.
// Base = round-15 (no-Pt, direct-L2 A-fragments; 147.3 us, k_fused 51.1).
// Latency model confirmed: waves ~93% stalled, SIMD idle ~0.93^4; need more
// INDEPENDENT blocks/SIMD, not more waves per block (r14 null explained).
// Round-16 change: X -> exactly 32KB so LDS caps at 5 blocks/CU (was 35.8KB
// -> 4).  X[64][256] f16 with 16B-unit XOR swizzle (unit ^= row&7; r11-
// verified pattern, 2-way max = free); gates live as f16 inside the X region
// (dead until epilogue-1 overwrites; +1 barrier pass1->ep1); red overlays X
// rows 0..1 (+1 barrier).  r15 proved barriers are free here (8->3 = no
// change), so +2 barriers is safe.  launch_bounds stays (256,4): allocator
// unconstrained (r11 spill lesson), HW computes 5 blocks from 32KB usage.
// Tripwires: VGPR must stay ~64, WRITE_SIZE must stay ~29MB (no spill).
// Falsifier: occupancy flat at ~33% + dur ~51 => occupancy lever dead.
// k_projpq / k_wprep unchanged (verified).
// ---------------------------------------------------------------------------

typedef _Float16 half8 __attribute__((ext_vector_type(8)));
typedef _Float16 half4v __attribute__((ext_vector_type(4)));
typedef float floatx4 __attribute__((ext_vector_type(4)));

#define MFMA16(a, b, c) __builtin_amdgcn_mfma_f32_16x16x32_f16((a), (b), (c), 0, 0, 0)

// ---------------- k_wprep: mats 0..15 -> MFMA f16 tiles (verified) ---------
__global__ __launch_bounds__(256) void k_wprep(
    const float* __restrict__ Wq, const float* __restrict__ Wk,
    const float* __restrict__ Wsub, const float* __restrict__ Wobj,
    const float* __restrict__ W1, _Float16* __restrict__ WT)
{
    int eid = blockIdx.x * 256 + threadIdx.x;     // 0..131071
    int mat = eid >> 13;                          // 0..15
    int rem = eid & 8191;
    int tileid = rem >> 6;
    int lane = rem & 63;
    const float* src;
    if      (mat < 6)  src = Wq + mat * 65536;
    else if (mat < 12) src = Wk + (mat - 6) * 65536;
    else if (mat == 12) src = Wsub;
    else if (mat == 13) src = Wobj;
    else if (mat == 14) src = W1;            // W1a: rows 0..255
    else               src = W1 + 65536;     // W1b: rows 256..511
    int nb = tileid >> 3, kb = tileid & 7;
    int n = nb * 16 + (lane & 15);
    int k = kb * 32 + (lane >> 4) * 8;
    half8 h;
    #pragma unroll
    for (int j = 0; j < 8; ++j) h[j] = (_Float16)src[(k + j) * 256 + n];
    *(half8*)(WT + mat * 65536 + tileid * 512 + lane * 8) = h;
}

// ---------------- k_projpq: M=16, 532 blocks + 32 W2-pack blocks -----------
__global__ __launch_bounds__(256) void k_projpq(
    const float* __restrict__ hs, _Float16* __restrict__ WT,
    const float* __restrict__ bq, const float* __restrict__ bk,
    const float* __restrict__ bsub, const float* __restrict__ bobj,
    const float* __restrict__ Wg, const float* __restrict__ W2,
    _Float16* __restrict__ PQt, _Float16* __restrict__ PKt,
    float* __restrict__ g_ws)
{
    int t = threadIdx.x;
    if (blockIdx.x >= 532) {           // W2 pack tail (verified pattern)
        int eid = (blockIdx.x - 532) * 256 + t;   // 0..8191
        int tileid = eid >> 6, lane = eid & 63;
        int nb = tileid >> 3, kb = tileid & 7;
        int n = nb * 16 + (lane & 15);
        int k = kb * 32 + (lane >> 4) * 8;
        half8 h;
        #pragma unroll
        for (int j = 0; j < 8; ++j) h[j] = (_Float16)W2[(k + j) * 256 + n];
        *(half8*)(WT + 16 * 65536 + tileid * 512 + lane * 8) = h;
        return;
    }

    __shared__ __align__(16) _Float16 Ah[16][264];   // hs f16; reused as Pst
    __shared__ __align__(16) _Float16 Xb[16][264];   // Q f16

    int lane = t & 63, wv = t >> 6;
    int mr = lane & 15, hf = lane >> 4;
    int u = blockIdx.x;
    int s = u / 19, rt = u - s * 19;
    int m0 = rt * 16;
    int qk = s & 1, rr = s >> 1;
    int l = rr % 7, b = rr / 7;
    int hs_l = (l < 6) ? l : 5;
    const float* src = hs + (hs_l * 2 + b) * 76800;
    int projmat = (l < 6) ? (qk * 6 + l) : (12 + qk);
    const _Float16* WprojT = WT + projmat * 65536;
    const _Float16* W1hT = WT + (14 + qk) * 65536;
    const float* bias = (l < 6) ? ((qk ? bk : bq) + l * 256) : (qk ? bobj : bsub);
    _Float16* dstP = qk ? PKt : PQt;
    const float* wvec = Wg + qk * 256;
    float* gdst = g_ws + qk * 4200 + (l * 2 + b) * 300;

    // stage 16 hs rows -> Ah f16 (16 threads/row, 16 cols each)
    {
        int row = t >> 4, qt = t & 15;
        int m = m0 + row; if (m > 299) m = 299;   // clamp; masked later
        const float* pp = src + m * 256 + qt * 16;
        #pragma unroll
        for (int i = 0; i < 4; ++i) {
            float4 v = *(const float4*)(pp + 4 * i);
            half4v h;
            h[0] = (_Float16)v.x; h[1] = (_Float16)v.y;
            h[2] = (_Float16)v.z; h[3] = (_Float16)v.w;
            *(half4v*)&Ah[row][qt * 16 + 4 * i] = h;
        }
    }
    __syncthreads();

    // GEMM1 (flipped): Q^T = Wproj^T @ hs^T   (unrolled: 32 L2 loads pipeline)
    floatx4 acc[4];
    #pragma unroll
    for (int i = 0; i < 4; ++i) acc[i] = floatx4{0.f, 0.f, 0.f, 0.f};
    #pragma unroll
    for (int ks = 0; ks < 8; ++ks) {
        half8 bfr = *(const half8*)&Ah[mr][ks * 32 + hf * 8];
        #pragma unroll
        for (int mt = 0; mt < 4; ++mt) {
            half8 afr = *(const half8*)(WprojT + (((wv * 4 + mt) * 8 + ks) << 9) + lane * 8);
            acc[mt] = MFMA16(afr, bfr, acc[mt]);
        }
    }
    #pragma unroll
    for (int mt = 0; mt < 4; ++mt) {
        int n0 = wv * 64 + mt * 16 + hf * 4;
        float4 bb = *(const float4*)&bias[n0];
        float bv[4] = {bb.x, bb.y, bb.z, bb.w};
        half4v h;
        #pragma unroll
        for (int u2 = 0; u2 < 4; ++u2) h[u2] = (_Float16)(acc[mt][u2] + bv[u2]);
        *(half4v*)&Xb[mr][n0] = h;
    }
    __syncthreads();

    // gq/gk row dots
    {
        int row = t >> 4, qt = t & 15;
        half8 x0 = *(const half8*)&Xb[row][qt * 16];
        half8 x1 = *(const half8*)&Xb[row][qt * 16 + 8];
        const float* wp = wvec + qt * 16;
        float sum = 0.f;
        #pragma unroll
        for (int i = 0; i < 8; ++i) sum += (float)x0[i] * wp[i];
        #pragma unroll
        for (int i = 0; i < 8; ++i) sum += (float)x1[i] * wp[8 + i];
        sum += __shfl_xor(sum, 1);
        sum += __shfl_xor(sum, 2);
        sum += __shfl_xor(sum, 4);
        sum += __shfl_xor(sum, 8);
        int m = m0 + row;
        if (qt == 0 && m < 300) gdst[m] = sum;
    }

    // GEMM2 (flipped): P^T = W1h^T @ Q^T   (unrolled)
    floatx4 acc2[4];
    #pragma unroll
    for (int i = 0; i < 4; ++i) acc2[i] = floatx4{0.f, 0.f, 0.f, 0.f};
    #pragma unroll
    for (int ks = 0; ks < 8; ++ks) {
        half8 bfr = *(const half8*)&Xb[mr][ks * 32 + hf * 8];
        #pragma unroll
        for (int mt = 0; mt < 4; ++mt) {
            half8 afr = *(const half8*)(W1hT + (((wv * 4 + mt) * 8 + ks) << 9) + lane * 8);
            acc2[mt] = MFMA16(afr, bfr, acc2[mt]);
        }
    }
    #pragma unroll
    for (int mt = 0; mt < 4; ++mt) {
        int n0 = wv * 64 + mt * 16 + hf * 4;
        half4v h;
        #pragma unroll
        for (int u2 = 0; u2 < 4; ++u2) h[u2] = (_Float16)acc2[mt][u2];
        *(half4v*)&Ah[mr][n0] = h;   // Pst reuse
    }
    __syncthreads();

    // coalesced store, l-major layout:
    //   dst[(((b*38+it)*7 + l)*256 + n)*8 + io], wave writes 1KB contiguous
    #pragma unroll
    for (int z = 0; z < 2; ++z) {
        int it = rt * 2 + z;
        int n = t;
        half8 h;
        #pragma unroll
        for (int io = 0; io < 8; ++io) h[io] = Ah[z * 8 + io][n];
        *(half8*)(dstP + ((size_t)((b * 38 + it) * 7 + l) * 256 + n) * 8) = h;
    }
}

// ---------------- k_fused: direct-L2 A-frags + 32KB swizzled X -------------
// grid 2*38*38 = 2888, block 256 (4 waves).  LDS = exactly 32768B:
//   phase gates: first 448 halves hold gate[l*64+r] f16 (dies after pass 1)
//   phase X    : X[r=64][n=256], 16B-unit XOR swizzle:
//                half addr = r*256 + ((n>>3)^(r&7))*8 + (n&7)
//   phase red  : first 256 floats (rows 0..1 region, X dead)
// 5 barriers; 5 blocks/CU static (was 4).
__global__ __launch_bounds__(256, 4) void k_fused(
    const _Float16* __restrict__ PQt, const _Float16* __restrict__ PKt,
    const float* __restrict__ g_ws, const float* __restrict__ b1,
    const _Float16* __restrict__ W2T, const float* __restrict__ b2,
    const float* __restrict__ W3, const float* __restrict__ b3,
    const float* __restrict__ bg, float* __restrict__ out)
{
    __shared__ __align__(16) _Float16 smh[16384];   // 32768 B exactly

    int t = threadIdx.x, lane = t & 63, wv = t >> 6;
    int mr = lane & 15, hf = lane >> 4;
    int bid = blockIdx.x;
    int b = bid / 1444, rem = bid - b * 1444;
    int it = rem / 38, jt = rem - it * 38;
    int i0 = it * 8, j0 = jt * 8;

    const _Float16* tQ = PQt + (size_t)((b * 38 + it) * 7) * 2048;
    const _Float16* tK = PKt + (size_t)((b * 38 + jt) * 7) * 2048;
    int l0 = hf;                        // ktl=0: l = 0..3 (always valid)
    int l1 = (hf == 3) ? 6 : 4 + hf;    // ktl=1: l = 4..6, clamp 7 -> 6

    // ---- prefetch pass-0 A fragments (8 x b128 from L2; covers gate math)
    half8 afrQ[2][4];
    #pragma unroll
    for (int mt = 0; mt < 4; ++mt) {
        size_t nb8 = (size_t)((wv * 64 + mt * 16 + mr) * 8);
        afrQ[0][mt] = *(const half8*)(tQ + l0 * 2048 + nb8);
        afrQ[1][mt] = *(const half8*)(tQ + l1 * 2048 + nb8);
    }

    // ---- gates (f16) -> smh[l*64+r] (X region; dies after pass 1) ----
    float bg0 = bg[0];
    for (int task = t; task < 448; task += 256) {
        int l = task >> 6, row = task & 63;
        int i = i0 + (row >> 3); if (i > 299) i = 299;
        int j = j0 + (row & 7);  if (j > 299) j = 299;
        float z = g_ws[l * 600 + b * 300 + i] + g_ws[4200 + l * 600 + b * 300 + j] + bg0;
        smh[l * 64 + row] = (_Float16)(1.0f / (1.0f + __expf(-z)));
    }
    __syncthreads();   // barrier 1: gates visible

    floatx4 acc1[4][4];
    #pragma unroll
    for (int i = 0; i < 4; ++i)
        #pragma unroll
        for (int j = 0; j < 4; ++j) acc1[i][j] = floatx4{0.f, 0.f, 0.f, 0.f};

    const _Float16 hz = (_Float16)0.f;

    // ---- pass 0, ktl=0 (l = hf): one-hot jstar = nt*2+(mr>>3) ----
    {
        half8 bfr[4];
        #pragma unroll
        for (int nt = 0; nt < 4; ++nt) {
            int r = nt * 16 + mr;
            _Float16 gh = smh[l0 * 64 + r];
            half8 f = {};
            f[nt * 2]     = (mr < 8)  ? gh : hz;
            f[nt * 2 + 1] = (mr >= 8) ? gh : hz;
            bfr[nt] = f;
        }
        #pragma unroll
        for (int mt = 0; mt < 4; ++mt)
            #pragma unroll
            for (int nt = 0; nt < 4; ++nt)
                acc1[mt][nt] = MFMA16(afrQ[0][mt], bfr[nt], acc1[mt][nt]);
    }

    // ---- prefetch pass-1 ktl=0 A fragments ----
    half8 afrK0[4];
    #pragma unroll
    for (int mt = 0; mt < 4; ++mt)
        afrK0[mt] = *(const half8*)(tK + l0 * 2048
                                    + (size_t)((wv * 64 + mt * 16 + mr) * 8));

    // ---- pass 0, ktl=1 (l = 4+hf; hf==3 -> l=7 -> gate 0) ----
    {
        half8 bfr[4];
        #pragma unroll
        for (int nt = 0; nt < 4; ++nt) {
            int r = nt * 16 + mr;
            _Float16 gh = (hf == 3) ? hz : smh[(4 + hf) * 64 + r];
            half8 f = {};
            f[nt * 2]     = (mr < 8)  ? gh : hz;
            f[nt * 2 + 1] = (mr >= 8) ? gh : hz;
            bfr[nt] = f;
        }
        #pragma unroll
        for (int mt = 0; mt < 4; ++mt)
            #pragma unroll
            for (int nt = 0; nt < 4; ++nt)
                acc1[mt][nt] = MFMA16(afrQ[1][mt], bfr[nt], acc1[mt][nt]);
    }

    // ---- prefetch pass-1 ktl=1 A fragments ----
    half8 afrK1[4];
    #pragma unroll
    for (int mt = 0; mt < 4; ++mt)
        afrK1[mt] = *(const half8*)(tK + l1 * 2048
                                    + (size_t)((wv * 64 + mt * 16 + mr) * 8));

    // ---- pass 1, ktl=0: one-hot jstar = mr & 7 ----
    {
        half8 bfr[4];
        #pragma unroll
        for (int nt = 0; nt < 4; ++nt) {
            int r = nt * 16 + mr;
            _Float16 gh = smh[l0 * 64 + r];
            half8 f = {};
            #pragma unroll
            for (int j = 0; j < 8; ++j)
                f[j] = (j == (mr & 7)) ? gh : hz;
            bfr[nt] = f;
        }
        #pragma unroll
        for (int mt = 0; mt < 4; ++mt)
            #pragma unroll
            for (int nt = 0; nt < 4; ++nt)
                acc1[mt][nt] = MFMA16(afrK0[mt], bfr[nt], acc1[mt][nt]);
    }

    // ---- pass 1, ktl=1 ----
    {
        half8 bfr[4];
        #pragma unroll
        for (int nt = 0; nt < 4; ++nt) {
            int r = nt * 16 + mr;
            _Float16 gh = (hf == 3) ? hz : smh[(4 + hf) * 64 + r];
            half8 f = {};
            #pragma unroll
            for (int j = 0; j < 8; ++j)
                f[j] = (j == (mr & 7)) ? gh : hz;
            bfr[nt] = f;
        }
        #pragma unroll
        for (int mt = 0; mt < 4; ++mt)
            #pragma unroll
            for (int nt = 0; nt < 4; ++nt)
                acc1[mt][nt] = MFMA16(afrK1[mt], bfr[nt], acc1[mt][nt]);
    }
    __syncthreads();   // barrier 2: all gate reads done; X may overwrite

    // ---- epilogue 1: relu(x1 + b1) -> X (swizzled), packed b64 ----
    #pragma unroll
    for (int mt = 0; mt < 4; ++mt) {
        int n0 = wv * 64 + mt * 16 + hf * 4;
        float4 bb = *(const float4*)&b1[n0];
        float bv[4] = {bb.x, bb.y, bb.z, bb.w};
        #pragma unroll
        for (int nt = 0; nt < 4; ++nt) {
            int r = nt * 16 + mr;
            half4v h;
            #pragma unroll
            for (int u = 0; u < 4; ++u) {
                float v = acc1[mt][nt][u] + bv[u];
                h[u] = (_Float16)(v > 0.f ? v : 0.f);
            }
            *(half4v*)&smh[r * 256 + (((n0 >> 3) ^ (r & 7)) << 3) + (n0 & 7)] = h;
        }
    }
    __syncthreads();   // barrier 3: X visible

    // ---- layer 2 (flipped): x2^T = W2^T @ x1^T (swizzled bfr reads) ----
    floatx4 acc2[4][4];
    #pragma unroll
    for (int i = 0; i < 4; ++i)
        #pragma unroll
        for (int j = 0; j < 4; ++j) acc2[i][j] = floatx4{0.f, 0.f, 0.f, 0.f};
    for (int s = 0; s < 8; ++s) {
        half8 bfr[4];
        #pragma unroll
        for (int nt = 0; nt < 4; ++nt) {
            int r = nt * 16 + mr;
            bfr[nt] = *(const half8*)&smh[r * 256 + (((s * 4 + hf) ^ (r & 7)) << 3)];
        }
        #pragma unroll
        for (int mt = 0; mt < 4; ++mt) {
            half8 afr = *(const half8*)(W2T + (((wv * 4 + mt) * 8 + s) << 9) + lane * 8);
            #pragma unroll
            for (int nt = 0; nt < 4; ++nt)
                acc2[mt][nt] = MFMA16(afr, bfr[nt], acc2[mt][nt]);
        }
    }

    // ---- fused epilogue 2 + layer 3: p[row] = relu(x2+b2) . W3 ----
    {
        float p[4] = {0.f, 0.f, 0.f, 0.f};
        #pragma unroll
        for (int mt = 0; mt < 4; ++mt) {
            int n0 = wv * 64 + mt * 16 + hf * 4;
            float4 bb = *(const float4*)&b2[n0];
            float4 w3 = *(const float4*)&W3[n0];
            float bv[4] = {bb.x, bb.y, bb.z, bb.w};
            float wv3[4] = {w3.x, w3.y, w3.z, w3.w};
            #pragma unroll
            for (int nt = 0; nt < 4; ++nt)
                #pragma unroll
                for (int u = 0; u < 4; ++u) {
                    float v = acc2[mt][nt][u] + bv[u];
                    v = v > 0.f ? v : 0.f;
                    p[nt] += v * wv3[u];
                }
        }
        #pragma unroll
        for (int nt = 0; nt < 4; ++nt) {
            p[nt] += __shfl_xor(p[nt], 16);
            p[nt] += __shfl_xor(p[nt], 32);
        }
        __syncthreads();   // barrier 4: all X reads done; red overlays X
        float* red = (float*)smh;           // 256 floats (X rows 0..1, dead)
        if (hf == 0) {
            #pragma unroll
            for (int nt = 0; nt < 4; ++nt)
                red[wv * 64 + nt * 16 + mr] = p[nt];
        }
        __syncthreads();   // barrier 5: red ready
        if (t < 64) {
            float pred = red[t] + red[64 + t] + red[128 + t] + red[192 + t] + b3[0];
            int i = i0 + (t >> 3), j = j0 + (t & 7);
            if (i < 300 && j < 300) {
                int base = b * 90000 + i * 300 + j;
                #pragma unroll
                for (int lo = 0; lo < 6; ++lo) out[lo * 180000 + base] = pred;
            }
        }
    }
}

// ---------------------------------------------------------------------------
extern "C" void kernel_launch(void* const* d_in, const int* in_sizes, int n_in,
                              void* d_out, int out_size, void* d_ws, size_t ws_size,
                              hipStream_t stream) {
    (void)in_sizes; (void)n_in; (void)out_size; (void)ws_size;
    const float* hs   = (const float*)d_in[0];
    const float* Wq   = (const float*)d_in[1];
    const float* bq   = (const float*)d_in[2];
    const float* Wk   = (const float*)d_in[3];
    const float* bk   = (const float*)d_in[4];
    const float* Wsub = (const float*)d_in[5];
    const float* bsub = (const float*)d_in[6];
    const float* Wobj = (const float*)d_in[7];
    const float* bobj = (const float*)d_in[8];
    const float* Wg   = (const float*)d_in[9];
    const float* bg   = (const float*)d_in[10];
    const float* W1   = (const float*)d_in[11];
    const float* b1   = (const float*)d_in[12];
    const float* W2   = (const float*)d_in[13];
    const float* b2   = (const float*)d_in[14];
    const float* W3   = (const float*)d_in[15];
    const float* b3   = (const float*)d_in[16];

    char* ws = (char*)d_ws;
    float* g_ws   = (float*)ws;                  // 8,400 f
    _Float16* WT  = (_Float16*)(ws + 33600);     // 17*65536 h
    _Float16* PQt = WT + 17 * 65536;             // 1,089,536 h (l-major layout)
    _Float16* PKt = PQt + 1089536;               // 1,089,536 h

    k_wprep<<<512, 256, 0, stream>>>(Wq, Wk, Wsub, Wobj, W1, WT);
    k_projpq<<<564, 256, 0, stream>>>(hs, WT, bq, bk, bsub, bobj, Wg, W2,
                                      PQt, PKt, g_ws);
    k_fused<<<2888, 256, 0, stream>>>(PQt, PKt, g_ws, b1, WT + 16 * 65536,
                                      b2, W3, b3, bg, (float*)d_out);
}

// Round 7
// 146.496 us; speedup vs baseline: 1.0152x; 1.0152x over previous
//
#include <hip/hip_runtime.h>

// ---------------------------------------------------------------------------
// CustomDeformableDetrMLPPredictionHead — MI355X (gfx950), round 17.
// Base = round-15 skeleton (no-Pt, direct-L2 A-frags).  Dead levers: blocks/CU
// (r11/12/16), LDS bandwidth (r13), waves/block (r14), barriers (r15), X
// swizzle (r16).  r15/16 WRITE_SIZE 29/57MB vs r10 6.4MB = scratch spill from
// 128 VGPR of resident A-fragments (unified VGPR+AGPR file).
// Round-17 changes:
//  (1) B-matrices in LDS: pass0/1 one-hot B (64x64 f16 each, IDENTICAL for
//      all 4 waves) built cooperatively once (448 gate tasks scatter one-hot
//      half8 rows; 64 tasks zero the l=7 chunk) -> per-lane bfr becomes one
//      ds_read_b128 instead of ~10-op VALU build x16.  Kills ~150 VALU/thread
//      off the serial chain and the hf==3 special-casing.
//  (2) A-frag loads depth-1 staggered (aA..aD, <=48 VGPR live) -> no spill.
//  LDS: union{B[2][64][72] 18.4KB, X[64][264] 33.8KB} = 33.8KB; plain X.
// Tripwires: VGPR <= ~84, WRITE_SIZE back to ~7-10MB.
// Falsifier: dur >= 50us with VALUBusy down => balanced-latency floor.
// k_projpq / k_wprep unchanged (verified).
// ---------------------------------------------------------------------------

typedef _Float16 half8 __attribute__((ext_vector_type(8)));
typedef _Float16 half4v __attribute__((ext_vector_type(4)));
typedef float floatx4 __attribute__((ext_vector_type(4)));

#define MFMA16(a, b, c) __builtin_amdgcn_mfma_f32_16x16x32_f16((a), (b), (c), 0, 0, 0)

// ---------------- k_wprep: mats 0..15 -> MFMA f16 tiles (verified) ---------
__global__ __launch_bounds__(256) void k_wprep(
    const float* __restrict__ Wq, const float* __restrict__ Wk,
    const float* __restrict__ Wsub, const float* __restrict__ Wobj,
    const float* __restrict__ W1, _Float16* __restrict__ WT)
{
    int eid = blockIdx.x * 256 + threadIdx.x;     // 0..131071
    int mat = eid >> 13;                          // 0..15
    int rem = eid & 8191;
    int tileid = rem >> 6;
    int lane = rem & 63;
    const float* src;
    if      (mat < 6)  src = Wq + mat * 65536;
    else if (mat < 12) src = Wk + (mat - 6) * 65536;
    else if (mat == 12) src = Wsub;
    else if (mat == 13) src = Wobj;
    else if (mat == 14) src = W1;            // W1a: rows 0..255
    else               src = W1 + 65536;     // W1b: rows 256..511
    int nb = tileid >> 3, kb = tileid & 7;
    int n = nb * 16 + (lane & 15);
    int k = kb * 32 + (lane >> 4) * 8;
    half8 h;
    #pragma unroll
    for (int j = 0; j < 8; ++j) h[j] = (_Float16)src[(k + j) * 256 + n];
    *(half8*)(WT + mat * 65536 + tileid * 512 + lane * 8) = h;
}

// ---------------- k_projpq: M=16, 532 blocks + 32 W2-pack blocks -----------
__global__ __launch_bounds__(256) void k_projpq(
    const float* __restrict__ hs, _Float16* __restrict__ WT,
    const float* __restrict__ bq, const float* __restrict__ bk,
    const float* __restrict__ bsub, const float* __restrict__ bobj,
    const float* __restrict__ Wg, const float* __restrict__ W2,
    _Float16* __restrict__ PQt, _Float16* __restrict__ PKt,
    float* __restrict__ g_ws)
{
    int t = threadIdx.x;
    if (blockIdx.x >= 532) {           // W2 pack tail (verified pattern)
        int eid = (blockIdx.x - 532) * 256 + t;   // 0..8191
        int tileid = eid >> 6, lane = eid & 63;
        int nb = tileid >> 3, kb = tileid & 7;
        int n = nb * 16 + (lane & 15);
        int k = kb * 32 + (lane >> 4) * 8;
        half8 h;
        #pragma unroll
        for (int j = 0; j < 8; ++j) h[j] = (_Float16)W2[(k + j) * 256 + n];
        *(half8*)(WT + 16 * 65536 + tileid * 512 + lane * 8) = h;
        return;
    }

    __shared__ __align__(16) _Float16 Ah[16][264];   // hs f16; reused as Pst
    __shared__ __align__(16) _Float16 Xb[16][264];   // Q f16

    int lane = t & 63, wv = t >> 6;
    int mr = lane & 15, hf = lane >> 4;
    int u = blockIdx.x;
    int s = u / 19, rt = u - s * 19;
    int m0 = rt * 16;
    int qk = s & 1, rr = s >> 1;
    int l = rr % 7, b = rr / 7;
    int hs_l = (l < 6) ? l : 5;
    const float* src = hs + (hs_l * 2 + b) * 76800;
    int projmat = (l < 6) ? (qk * 6 + l) : (12 + qk);
    const _Float16* WprojT = WT + projmat * 65536;
    const _Float16* W1hT = WT + (14 + qk) * 65536;
    const float* bias = (l < 6) ? ((qk ? bk : bq) + l * 256) : (qk ? bobj : bsub);
    _Float16* dstP = qk ? PKt : PQt;
    const float* wvec = Wg + qk * 256;
    float* gdst = g_ws + qk * 4200 + (l * 2 + b) * 300;

    // stage 16 hs rows -> Ah f16 (16 threads/row, 16 cols each)
    {
        int row = t >> 4, qt = t & 15;
        int m = m0 + row; if (m > 299) m = 299;   // clamp; masked later
        const float* pp = src + m * 256 + qt * 16;
        #pragma unroll
        for (int i = 0; i < 4; ++i) {
            float4 v = *(const float4*)(pp + 4 * i);
            half4v h;
            h[0] = (_Float16)v.x; h[1] = (_Float16)v.y;
            h[2] = (_Float16)v.z; h[3] = (_Float16)v.w;
            *(half4v*)&Ah[row][qt * 16 + 4 * i] = h;
        }
    }
    __syncthreads();

    // GEMM1 (flipped): Q^T = Wproj^T @ hs^T   (unrolled: 32 L2 loads pipeline)
    floatx4 acc[4];
    #pragma unroll
    for (int i = 0; i < 4; ++i) acc[i] = floatx4{0.f, 0.f, 0.f, 0.f};
    #pragma unroll
    for (int ks = 0; ks < 8; ++ks) {
        half8 bfr = *(const half8*)&Ah[mr][ks * 32 + hf * 8];
        #pragma unroll
        for (int mt = 0; mt < 4; ++mt) {
            half8 afr = *(const half8*)(WprojT + (((wv * 4 + mt) * 8 + ks) << 9) + lane * 8);
            acc[mt] = MFMA16(afr, bfr, acc[mt]);
        }
    }
    #pragma unroll
    for (int mt = 0; mt < 4; ++mt) {
        int n0 = wv * 64 + mt * 16 + hf * 4;
        float4 bb = *(const float4*)&bias[n0];
        float bv[4] = {bb.x, bb.y, bb.z, bb.w};
        half4v h;
        #pragma unroll
        for (int u2 = 0; u2 < 4; ++u2) h[u2] = (_Float16)(acc[mt][u2] + bv[u2]);
        *(half4v*)&Xb[mr][n0] = h;
    }
    __syncthreads();

    // gq/gk row dots
    {
        int row = t >> 4, qt = t & 15;
        half8 x0 = *(const half8*)&Xb[row][qt * 16];
        half8 x1 = *(const half8*)&Xb[row][qt * 16 + 8];
        const float* wp = wvec + qt * 16;
        float sum = 0.f;
        #pragma unroll
        for (int i = 0; i < 8; ++i) sum += (float)x0[i] * wp[i];
        #pragma unroll
        for (int i = 0; i < 8; ++i) sum += (float)x1[i] * wp[8 + i];
        sum += __shfl_xor(sum, 1);
        sum += __shfl_xor(sum, 2);
        sum += __shfl_xor(sum, 4);
        sum += __shfl_xor(sum, 8);
        int m = m0 + row;
        if (qt == 0 && m < 300) gdst[m] = sum;
    }

    // GEMM2 (flipped): P^T = W1h^T @ Q^T   (unrolled)
    floatx4 acc2[4];
    #pragma unroll
    for (int i = 0; i < 4; ++i) acc2[i] = floatx4{0.f, 0.f, 0.f, 0.f};
    #pragma unroll
    for (int ks = 0; ks < 8; ++ks) {
        half8 bfr = *(const half8*)&Xb[mr][ks * 32 + hf * 8];
        #pragma unroll
        for (int mt = 0; mt < 4; ++mt) {
            half8 afr = *(const half8*)(W1hT + (((wv * 4 + mt) * 8 + ks) << 9) + lane * 8);
            acc2[mt] = MFMA16(afr, bfr, acc2[mt]);
        }
    }
    #pragma unroll
    for (int mt = 0; mt < 4; ++mt) {
        int n0 = wv * 64 + mt * 16 + hf * 4;
        half4v h;
        #pragma unroll
        for (int u2 = 0; u2 < 4; ++u2) h[u2] = (_Float16)acc2[mt][u2];
        *(half4v*)&Ah[mr][n0] = h;   // Pst reuse
    }
    __syncthreads();

    // coalesced store, l-major layout:
    //   dst[(((b*38+it)*7 + l)*256 + n)*8 + io], wave writes 1KB contiguous
    #pragma unroll
    for (int z = 0; z < 2; ++z) {
        int it = rt * 2 + z;
        int n = t;
        half8 h;
        #pragma unroll
        for (int io = 0; io < 8; ++io) h[io] = Ah[z * 8 + io][n];
        *(half8*)(dstP + ((size_t)((b * 38 + it) * 7 + l) * 256 + n) * 8) = h;
    }
}

// ---------------- k_fused: LDS B-matrices + staggered direct-L2 A ----------
// grid 2*38*38 = 2888, block 256 (4 waves).
// B_p[r][k], k = l*8+j: gate[l][r] at j = jstar_p(r) (p0: r>>3, p1: r&7),
// rows padded to 72 halves (2-way bank max).  Shared by all 4 waves.
// A-frag groups aA..aD loaded depth-1 ahead (<=48 VGPR live, no spill).
// 5 barriers.  LDS = union{B 18.4KB, X 33.8KB} = 33,792 B.
__global__ __launch_bounds__(256, 4) void k_fused(
    const _Float16* __restrict__ PQt, const _Float16* __restrict__ PKt,
    const float* __restrict__ g_ws, const float* __restrict__ b1,
    const _Float16* __restrict__ W2T, const float* __restrict__ b2,
    const float* __restrict__ W3, const float* __restrict__ b3,
    const float* __restrict__ bg, float* __restrict__ out)
{
    union SMu {
        _Float16 B[2][64][72];   // [pass][r][k(l*8+j)]; 18,432 B
        _Float16 X[64][264];     // x1; 33,792 B; red overlays rows 0..1
    };
    __shared__ __align__(16) SMu sm;

    int t = threadIdx.x, lane = t & 63, wv = t >> 6;
    int mr = lane & 15, hf = lane >> 4;
    int bid = blockIdx.x;
    int b = bid / 1444, rem = bid - b * 1444;
    int it = rem / 38, jt = rem - it * 38;
    int i0 = it * 8, j0 = jt * 8;

    const _Float16* tQ = PQt + (size_t)((b * 38 + it) * 7) * 2048;
    const _Float16* tK = PKt + (size_t)((b * 38 + jt) * 7) * 2048;
    int l0 = hf;                        // ktl=0: l = 0..3 (always valid)
    int l1 = (hf == 3) ? 6 : 4 + hf;    // ktl=1: l = 4..6; 7 clamped (B k-chunk
                                        // 56..63 is zeroed, so A just finite)
    int nb8[4];
    #pragma unroll
    for (int mt = 0; mt < 4; ++mt) nb8[mt] = (wv * 64 + mt * 16 + mr) * 8;

    // ---- A group 0 (pass0 ktl0) early: L2 latency hides under gate math ---
    half8 aA[4];
    #pragma unroll
    for (int mt = 0; mt < 4; ++mt)
        aA[mt] = *(const half8*)(tQ + l0 * 2048 + nb8[mt]);

    // ---- build B0/B1 cooperatively (512 tasks over 256 threads) ----
    _Float16* Bf = &sm.B[0][0][0];
    float bg0 = bg[0];
    #pragma unroll
    for (int half = 0; half < 2; ++half) {
        int task = t + half * 256;
        if (task < 448) {
            int l = task >> 6, r = task & 63;
            int i = i0 + (r >> 3); if (i > 299) i = 299;
            int j = j0 + (r & 7);  if (j > 299) j = 299;
            float z = g_ws[l * 600 + b * 300 + i]
                    + g_ws[4200 + l * 600 + b * 300 + j] + bg0;
            _Float16 gh = (_Float16)(1.0f / (1.0f + __expf(-z)));
            const _Float16 hz0 = (_Float16)0.f;
            int s0 = r >> 3, s1 = r & 7;
            half8 f0, f1;
            #pragma unroll
            for (int u = 0; u < 8; ++u) {
                f0[u] = (u == s0) ? gh : hz0;
                f1[u] = (u == s1) ? gh : hz0;
            }
            *(half8*)&Bf[(size_t)r * 72 + l * 8] = f0;
            *(half8*)&Bf[4608 + (size_t)r * 72 + l * 8] = f1;
        } else {
            int r = task - 448;              // 0..63: zero l=7 chunks
            *(half8*)&Bf[(size_t)r * 72 + 56] = half8{};
            *(half8*)&Bf[4608 + (size_t)r * 72 + 56] = half8{};
        }
    }
    __syncthreads();   // barrier 1: B0/B1 ready

    floatx4 acc1[4][4];
    #pragma unroll
    for (int i = 0; i < 4; ++i)
        #pragma unroll
        for (int j = 0; j < 4; ++j) acc1[i][j] = floatx4{0.f, 0.f, 0.f, 0.f};

    // ---- g0: pass0 ktl0 (A = aA); prefetch aB = Q.l1 ----
    {
        half8 bfr[4];
        #pragma unroll
        for (int nt = 0; nt < 4; ++nt)
            bfr[nt] = *(const half8*)&Bf[(size_t)(nt * 16 + mr) * 72 + hf * 8];
        half8 aB[4];
        #pragma unroll
        for (int mt = 0; mt < 4; ++mt)
            aB[mt] = *(const half8*)(tQ + l1 * 2048 + nb8[mt]);
        #pragma unroll
        for (int mt = 0; mt < 4; ++mt)
            #pragma unroll
            for (int nt = 0; nt < 4; ++nt)
                acc1[mt][nt] = MFMA16(aA[mt], bfr[nt], acc1[mt][nt]);

        // ---- g1: pass0 ktl1 (A = aB); prefetch aC = K.l0 ----
        half8 bfr1[4];
        #pragma unroll
        for (int nt = 0; nt < 4; ++nt)
            bfr1[nt] = *(const half8*)&Bf[(size_t)(nt * 16 + mr) * 72 + 32 + hf * 8];
        half8 aC[4];
        #pragma unroll
        for (int mt = 0; mt < 4; ++mt)
            aC[mt] = *(const half8*)(tK + l0 * 2048 + nb8[mt]);
        #pragma unroll
        for (int mt = 0; mt < 4; ++mt)
            #pragma unroll
            for (int nt = 0; nt < 4; ++nt)
                acc1[mt][nt] = MFMA16(aB[mt], bfr1[nt], acc1[mt][nt]);

        // ---- g2: pass1 ktl0 (A = aC); prefetch aD = K.l1 ----
        half8 bfr2[4];
        #pragma unroll
        for (int nt = 0; nt < 4; ++nt)
            bfr2[nt] = *(const half8*)&Bf[4608 + (size_t)(nt * 16 + mr) * 72 + hf * 8];
        half8 aD[4];
        #pragma unroll
        for (int mt = 0; mt < 4; ++mt)
            aD[mt] = *(const half8*)(tK + l1 * 2048 + nb8[mt]);
        #pragma unroll
        for (int mt = 0; mt < 4; ++mt)
            #pragma unroll
            for (int nt = 0; nt < 4; ++nt)
                acc1[mt][nt] = MFMA16(aC[mt], bfr2[nt], acc1[mt][nt]);

        // ---- g3: pass1 ktl1 (A = aD) ----
        half8 bfr3[4];
        #pragma unroll
        for (int nt = 0; nt < 4; ++nt)
            bfr3[nt] = *(const half8*)&Bf[4608 + (size_t)(nt * 16 + mr) * 72 + 32 + hf * 8];
        #pragma unroll
        for (int mt = 0; mt < 4; ++mt)
            #pragma unroll
            for (int nt = 0; nt < 4; ++nt)
                acc1[mt][nt] = MFMA16(aD[mt], bfr3[nt], acc1[mt][nt]);
    }
    __syncthreads();   // barrier 2: B reads done; X may overwrite union

    // ---- epilogue 1: relu(x1 + b1) -> X[r][n], packed b64 ----
    #pragma unroll
    for (int mt = 0; mt < 4; ++mt) {
        int n0 = wv * 64 + mt * 16 + hf * 4;
        float4 bb = *(const float4*)&b1[n0];
        float bv[4] = {bb.x, bb.y, bb.z, bb.w};
        #pragma unroll
        for (int nt = 0; nt < 4; ++nt) {
            int r = nt * 16 + mr;
            half4v h;
            #pragma unroll
            for (int u = 0; u < 4; ++u) {
                float v = acc1[mt][nt][u] + bv[u];
                h[u] = (_Float16)(v > 0.f ? v : 0.f);
            }
            *(half4v*)&sm.X[r][n0] = h;
        }
    }
    __syncthreads();   // barrier 3: X visible

    // ---- layer 2 (flipped): x2^T = W2^T @ x1^T ----
    floatx4 acc2[4][4];
    #pragma unroll
    for (int i = 0; i < 4; ++i)
        #pragma unroll
        for (int j = 0; j < 4; ++j) acc2[i][j] = floatx4{0.f, 0.f, 0.f, 0.f};
    for (int s = 0; s < 8; ++s) {
        half8 bfr[4];
        #pragma unroll
        for (int nt = 0; nt < 4; ++nt)
            bfr[nt] = *(const half8*)&sm.X[nt * 16 + mr][s * 32 + hf * 8];
        #pragma unroll
        for (int mt = 0; mt < 4; ++mt) {
            half8 afr = *(const half8*)(W2T + (((wv * 4 + mt) * 8 + s) << 9) + lane * 8);
            #pragma unroll
            for (int nt = 0; nt < 4; ++nt)
                acc2[mt][nt] = MFMA16(afr, bfr[nt], acc2[mt][nt]);
        }
    }

    // ---- fused epilogue 2 + layer 3: p[row] = relu(x2+b2) . W3 ----
    {
        float p[4] = {0.f, 0.f, 0.f, 0.f};
        #pragma unroll
        for (int mt = 0; mt < 4; ++mt) {
            int n0 = wv * 64 + mt * 16 + hf * 4;
            float4 bb = *(const float4*)&b2[n0];
            float4 w3 = *(const float4*)&W3[n0];
            float bv[4] = {bb.x, bb.y, bb.z, bb.w};
            float wv3[4] = {w3.x, w3.y, w3.z, w3.w};
            #pragma unroll
            for (int nt = 0; nt < 4; ++nt)
                #pragma unroll
                for (int u = 0; u < 4; ++u) {
                    float v = acc2[mt][nt][u] + bv[u];
                    v = v > 0.f ? v : 0.f;
                    p[nt] += v * wv3[u];
                }
        }
        #pragma unroll
        for (int nt = 0; nt < 4; ++nt) {
            p[nt] += __shfl_xor(p[nt], 16);
            p[nt] += __shfl_xor(p[nt], 32);
        }
        __syncthreads();   // barrier 4: all X reads done; red overlays X
        float* red = (float*)&sm.X[0][0];   // 256 floats (X rows 0..1, dead)
        if (hf == 0) {
            #pragma unroll
            for (int nt = 0; nt < 4; ++nt)
                red[wv * 64 + nt * 16 + mr] = p[nt];
        }
        __syncthreads();   // barrier 5: red ready
        if (t < 64) {
            float pred = red[t] + red[64 + t] + red[128 + t] + red[192 + t] + b3[0];
            int i = i0 + (t >> 3), j = j0 + (t & 7);
            if (i < 300 && j < 300) {
                int base = b * 90000 + i * 300 + j;
                #pragma unroll
                for (int lo = 0; lo < 6; ++lo) out[lo * 180000 + base] = pred;
            }
        }
    }
}

// ---------------------------------------------------------------------------
extern "C" void kernel_launch(void* const* d_in, const int* in_sizes, int n_in,
                              void* d_out, int out_size, void* d_ws, size_t ws_size,
                              hipStream_t stream) {
    (void)in_sizes; (void)n_in; (void)out_size; (void)ws_size;
    const float* hs   = (const float*)d_in[0];
    const float* Wq   = (const float*)d_in[1];
    const float* bq   = (const float*)d_in[2];
    const float* Wk   = (const float*)d_in[3];
    const float* bk   = (const float*)d_in[4];
    const float* Wsub = (const float*)d_in[5];
    const float* bsub = (const float*)d_in[6];
    const float* Wobj = (const float*)d_in[7];
    const float* bobj = (const float*)d_in[8];
    const float* Wg   = (const float*)d_in[9];
    const float* bg   = (const float*)d_in[10];
    const float* W1   = (const float*)d_in[11];
    const float* b1   = (const float*)d_in[12];
    const float* W2   = (const float*)d_in[13];
    const float* b2   = (const float*)d_in[14];
    const float* W3   = (const float*)d_in[15];
    const float* b3   = (const float*)d_in[16];

    char* ws = (char*)d_ws;
    float* g_ws   = (float*)ws;                  // 8,400 f
    _Float16* WT  = (_Float16*)(ws + 33600);     // 17*65536 h
    _Float16* PQt = WT + 17 * 65536;             // 1,089,536 h (l-major layout)
    _Float16* PKt = PQt + 1089536;               // 1,089,536 h

    k_wprep<<<512, 256, 0, stream>>>(Wq, Wk, Wsub, Wobj, W1, WT);
    k_projpq<<<564, 256, 0, stream>>>(hs, WT, bq, bk, bsub, bobj, Wg, W2,
                                      PQt, PKt, g_ws);
    k_fused<<<2888, 256, 0, stream>>>(PQt, PKt, g_ws, b1, WT + 16 * 65536,
                                      b2, W3, b3, bg, (float*)d_out);
}